// Round 14
// baseline (283.260 us; speedup 1.0000x reference)
//
#include <hip/hip_runtime.h>
#include <hip/hip_cooperative_groups.h>

namespace cg = cooperative_groups;

#define IN_FEAT 4096
#define OUT_FEAT 4096
#define RANK 64
#define NROWS 16384
#define TM 32              // phase-A rows per sub-tile
#define BT 512             // threads per block (8 waves)
#define NB 256             // grid blocks (1 per CU)
#define KC2 256            // phase-A K-chunk (f32 elems)
#define SXS 264            // xs inner stride (f16)
#define BR 256             // phase-B tile rows
#define BC 256             // phase-B tile cols
#define BS 72              // phase-B LDS inner stride (f16)
#define KC 256             // fallback kernel chunk
#define WA_STRIDE 264
#define XP_STRIDE 72

// ABLATION KNOB: run phase A this many times (2 = measure T_A by duplication)
#define PHASE_A_REPS 2

typedef _Float16 half_t;
typedef _Float16 f16x4 __attribute__((ext_vector_type(4)));
typedef _Float16 f16x8 __attribute__((ext_vector_type(8)));
typedef float f32x4 __attribute__((ext_vector_type(4)));

__device__ __forceinline__ f16x4 thr4(float4 v, float s) {
    float a0 = fabsf(v.x), a1 = fabsf(v.y), a2 = fabsf(v.z), a3 = fabsf(v.w);
    float lo1 = fminf(a0, a1), hi1 = fmaxf(a0, a1);
    float lo2 = fminf(a2, a3), hi2 = fmaxf(a2, a3);
    float t = fminf(fmaxf(lo1, lo2), fminf(hi1, hi2));  // 2nd-smallest = 3rd-largest
    f16x4 r;
    r[0] = (half_t)(copysignf(fmaxf(a0 - t, 0.0f), v.x) * s);
    r[1] = (half_t)(copysignf(fmaxf(a1 - t, 0.0f), v.y) * s);
    r[2] = (half_t)(copysignf(fmaxf(a2 - t, 0.0f), v.z) * s);
    r[3] = (half_t)(copysignf(fmaxf(a3 - t, 0.0f), v.w) * s);
    return r;
}

__device__ __forceinline__ f16x4 cvt4(f32x4 v) {
    f16x4 h;
    h[0] = (half_t)v[0]; h[1] = (half_t)v[1];
    h[2] = (half_t)v[2]; h[3] = (half_t)v[3];
    return h;
}

// ============ v3b + phase-A duplication (diagnostic ablation) ===============
__global__ __launch_bounds__(BT) void coop_v3(
    const float* __restrict__ x, const float* __restrict__ wA,
    const float* __restrict__ wB, const float* __restrict__ bias,
    const float* __restrict__ scaleA, const float* __restrict__ scaleB,
    float* __restrict__ out, half_t* __restrict__ wAT, half_t* __restrict__ wBh,
    half_t* __restrict__ xpw)
{
    __shared__ __align__(16) char pool[BR * BS * 2 + BC * BS * 2]; // 72 KB
    __shared__ float biasl[BC];                                    // 1 KB

    int tid = threadIdx.x;
    int bid = blockIdx.x;

    // ---- Phase 0: prep weights ----------------------------------------------
    {
        int id = bid * BT + tid;
        if (id < 65536) {
            int row = id >> 4;
            int gq  = id & 15;
            float s = scaleB[0];
            f16x4 h = thr4(*(const float4*)(wB + (size_t)row * RANK + gq * 4), s);
            *(f16x4*)(wBh + (size_t)row * RANK + gq * 4) = h;
        } else if (id < 65536 + 8192) {
            int t2 = id - 65536;
            int c4 = t2 & 15;
            int k8 = t2 >> 4;
            float s = scaleA[0];
            f16x8 vc0, vc1, vc2, vc3;
#pragma unroll
            for (int i = 0; i < 8; ++i) {
                float4 v = *(const float4*)(wA + (size_t)(k8 * 8 + i) * RANK + c4 * 4);
                f16x4 h = thr4(v, s);
                vc0[i] = h[0]; vc1[i] = h[1]; vc2[i] = h[2]; vc3[i] = h[3];
            }
            *(f16x8*)(wAT + (size_t)(c4 * 4 + 0) * IN_FEAT + k8 * 8) = vc0;
            *(f16x8*)(wAT + (size_t)(c4 * 4 + 1) * IN_FEAT + k8 * 8) = vc1;
            *(f16x8*)(wAT + (size_t)(c4 * 4 + 2) * IN_FEAT + k8 * 8) = vc2;
            *(f16x8*)(wAT + (size_t)(c4 * 4 + 3) * IN_FEAT + k8 * 8) = vc3;
        }
    }
    cg::this_grid().sync();

    int wave = tid >> 6;
    int lane = tid & 63;
    int l16  = lane & 15;
    int g    = lane >> 4;

    // ---- Phase A (x PHASE_A_REPS): two 32-row tiles -> xpw ------------------
    {
        half_t (*xs)[TM][SXS] = (half_t(*)[TM][SXS])pool;
        int stripe = wave & 1;
        int quad   = wave >> 1;
        int srow = tid >> 4;
        int sseg = tid & 15;

        for (int rep = 0; rep < PHASE_A_REPS; ++rep) {
            for (int sub = 0; sub < 2; ++sub) {
                int rowbase = bid * (2 * TM) + sub * TM;
                const float* srcrow = x + (size_t)(rowbase + srow) * IN_FEAT + sseg * 4;

                {   // prologue: stage chunk 0
                    const f32x4* p = (const f32x4*)(srcrow);
                    f32x4 a0 = p[0], a1 = p[16], a2 = p[32], a3 = p[48];
                    half_t* dst = &xs[0][srow][sseg * 4];
                    *(f16x4*)(dst +   0) = cvt4(a0);
                    *(f16x4*)(dst +  64) = cvt4(a1);
                    *(f16x4*)(dst + 128) = cvt4(a2);
                    *(f16x4*)(dst + 192) = cvt4(a3);
                }
                __syncthreads();

                f32x4 acc = {0, 0, 0, 0};
                const half_t* wcol = wAT + (size_t)(quad * 16 + l16) * IN_FEAT;
                const half_t* arow = &xs[0][stripe * 16 + l16][0];
                const int xsstep = TM * SXS;
                f32x4 ld0, ld1, ld2, ld3;

                for (int c = 0; c < IN_FEAT / KC2; ++c) {
                    f16x8 bfr[8];
#pragma unroll
                    for (int j = 0; j < 8; ++j)
                        bfr[j] = *(const f16x8*)(wcol + c * KC2 + j * 32 + 8 * g);
                    __builtin_amdgcn_sched_barrier(0);
                    if (c + 1 < IN_FEAT / KC2) {
                        const f32x4* p = (const f32x4*)(srcrow + (c + 1) * KC2);
                        ld0 = p[0]; ld1 = p[16]; ld2 = p[32]; ld3 = p[48];
                    }
                    __builtin_amdgcn_sched_barrier(0);

                    const half_t* ar = arow + (c & 1) * xsstep;
#pragma unroll
                    for (int j = 0; j < 8; ++j) {
                        f16x8 a = *(const f16x8*)(ar + j * 32 + 8 * g);
                        acc = __builtin_amdgcn_mfma_f32_16x16x32_f16(a, bfr[j], acc, 0, 0, 0);
                    }
                    if (c + 1 < IN_FEAT / KC2) {
                        half_t* dst = &xs[(c + 1) & 1][srow][sseg * 4];
                        *(f16x4*)(dst +   0) = cvt4(ld0);
                        *(f16x4*)(dst +  64) = cvt4(ld1);
                        *(f16x4*)(dst + 128) = cvt4(ld2);
                        *(f16x4*)(dst + 192) = cvt4(ld3);
                    }
                    __syncthreads();
                }

                // C/D: col = lane&15, row = 4*(lane>>4)+reg; full-K f32 -> f16
#pragma unroll
                for (int r = 0; r < 4; ++r)
                    xpw[(size_t)(rowbase + stripe * 16 + 4 * g + r) * RANK + quad * 16 + l16]
                        = (half_t)acc[r];
                __syncthreads();   // xs fully free before next sub-tile
            }
        }
    }
    cg::this_grid().sync();

    // ---- Phase B: 256-row slab x 4 fat 256-col tiles ------------------------
    {
        half_t (*xps)[BS] = (half_t(*)[BS])pool;                       // 36 KB
        half_t (*wbs)[BS] = (half_t(*)[BS])(pool + BR * BS * 2);       // 36 KB

        int rb = (bid >> 2) * BR;

        {
            int row = tid >> 1, h = tid & 1;
            const half_t* src = xpw + (size_t)(rb + row) * RANK + h * 32;
            f16x8 v0 = *(const f16x8*)(src + 0);
            f16x8 v1 = *(const f16x8*)(src + 8);
            f16x8 v2 = *(const f16x8*)(src + 16);
            f16x8 v3 = *(const f16x8*)(src + 24);
            half_t* dst = &xps[row][h * 32];
            *(f16x8*)(dst + 0)  = v0;
            *(f16x8*)(dst + 8)  = v1;
            *(f16x8*)(dst + 16) = v2;
            *(f16x8*)(dst + 24) = v3;
        }

        int wrow = (wave & 1) * 128;
        int wcol = (wave >> 1) * 64;

        for (int t = 0; t < 4; ++t) {
            int cb = ((bid & 3) * 4 + t) * BC;

            {
                int col = tid >> 1, h = tid & 1;
                const half_t* src = wBh + (size_t)(cb + col) * RANK + h * 32;
                f16x8 v0 = *(const f16x8*)(src + 0);
                f16x8 v1 = *(const f16x8*)(src + 8);
                f16x8 v2 = *(const f16x8*)(src + 16);
                f16x8 v3 = *(const f16x8*)(src + 24);
                half_t* dst = &wbs[col][h * 32];
                *(f16x8*)(dst + 0)  = v0;
                *(f16x8*)(dst + 8)  = v1;
                *(f16x8*)(dst + 16) = v2;
                *(f16x8*)(dst + 24) = v3;
                if (tid < BC) biasl[tid] = bias[cb + tid];
            }
            __syncthreads();

            f16x8 bf0[4], bf1[4];
            float bv[4];
#pragma unroll
            for (int ci = 0; ci < 4; ++ci) {
                int c16 = wcol + ci * 16 + l16;
                bf0[ci] = *(const f16x8*)&wbs[c16][8 * g];
                bf1[ci] = *(const f16x8*)&wbs[c16][32 + 8 * g];
                bv[ci]  = biasl[c16];
            }

            for (int rt = 0; rt < 8; ++rt) {
                const half_t* ar = &xps[wrow + rt * 16 + l16][0];
                f16x8 a0 = *(const f16x8*)(ar + 8 * g);
                f16x8 a1 = *(const f16x8*)(ar + 32 + 8 * g);
                int row0 = rb + wrow + rt * 16 + 4 * g;
#pragma unroll
                for (int ci = 0; ci < 4; ++ci) {
                    f32x4 acc2 = {0, 0, 0, 0};
                    acc2 = __builtin_amdgcn_mfma_f32_16x16x32_f16(a0, bf0[ci], acc2, 0, 0, 0);
                    acc2 = __builtin_amdgcn_mfma_f32_16x16x32_f16(a1, bf1[ci], acc2, 0, 0, 0);
                    int col = cb + wcol + ci * 16 + l16;
#pragma unroll
                    for (int r = 0; r < 4; ++r)
                        out[(size_t)(row0 + r) * OUT_FEAT + col] = acc2[r] + bv[ci];
                }
            }
            __syncthreads();
        }
    }
}

// ================= fallback: zero-ws fused (round-4, passing) ===============
__global__ __launch_bounds__(256) void fused_kernel(
    const float* __restrict__ x, const float* __restrict__ wA,
    const float* __restrict__ wB, const float* __restrict__ bias,
    const float* __restrict__ scaleA, const float* __restrict__ scaleB,
    float* __restrict__ out)
{
    __shared__ __align__(16) half_t wAsT[RANK][WA_STRIDE];
    __shared__ float xp_part[2][TM][XP_STRIDE];
    __shared__ __align__(16) half_t xp[TM][XP_STRIDE];

    int tid  = threadIdx.x;
    int wave = tid >> 6;
    int lane = tid & 63;
    int l16  = lane & 15;
    int g    = lane >> 4;
    int rowbase = blockIdx.x * TM;
    int stripe  = wave & 1;
    int ks      = wave >> 1;

    float sA = scaleA[0];
    float sB = scaleB[0];

    const float* xrow = x + (size_t)(rowbase + stripe * 16 + l16) * IN_FEAT;
    f32x4 acc[4] = {f32x4{0,0,0,0}, f32x4{0,0,0,0}, f32x4{0,0,0,0}, f32x4{0,0,0,0}};

    for (int chunk = 0; chunk < IN_FEAT / KC; ++chunk) {
        int k0 = chunk * KC;
#pragma unroll
        for (int pp = 0; pp < 2; ++pp) {
            int p = tid + pp * 256;
            int q = p & 15;
            int r = p >> 4;
            f16x8 vc0, vc1, vc2, vc3;
#pragma unroll
            for (int i = 0; i < 8; ++i) {
                float4 v = *(const float4*)(wA + (size_t)(k0 + 8 * r + i) * RANK + 4 * q);
                f16x4 h = thr4(v, sA);
                vc0[i] = h[0]; vc1[i] = h[1]; vc2[i] = h[2]; vc3[i] = h[3];
            }
            *(f16x8*)&wAsT[4 * q + 0][8 * r] = vc0;
            *(f16x8*)&wAsT[4 * q + 1][8 * r] = vc1;
            *(f16x8*)&wAsT[4 * q + 2][8 * r] = vc2;
            *(f16x8*)&wAsT[4 * q + 3][8 * r] = vc3;
        }
        __syncthreads();

#pragma unroll
        for (int it = 0; it < 4; ++it) {
            int kloc = ks * 128 + it * 32;
            float4 xa = *(const float4*)(xrow + k0 + kloc + 8 * g);
            float4 xb = *(const float4*)(xrow + k0 + kloc + 8 * g + 4);
            f16x8 a;
            a[0] = (half_t)xa.x; a[1] = (half_t)xa.y; a[2] = (half_t)xa.z; a[3] = (half_t)xa.w;
            a[4] = (half_t)xb.x; a[5] = (half_t)xb.y; a[6] = (half_t)xb.z; a[7] = (half_t)xb.w;
#pragma unroll
            for (int f = 0; f < 4; ++f) {
                f16x8 b = *(const f16x8*)&wAsT[16 * f + l16][kloc + 8 * g];
                acc[f] = __builtin_amdgcn_mfma_f32_16x16x32_f16(a, b, acc[f], 0, 0, 0);
            }
        }
        __syncthreads();
    }

#pragma unroll
    for (int f = 0; f < 4; ++f)
#pragma unroll
        for (int r = 0; r < 4; ++r)
            xp_part[ks][stripe * 16 + 4 * g + r][16 * f + l16] = acc[f][r];
    __syncthreads();

#pragma unroll
    for (int i = 0; i < (TM * RANK) / 256; ++i) {
        int e = i * 256 + tid;
        int r = e >> 6, c = e & 63;
        xp[r][c] = (half_t)(xp_part[0][r][c] + xp_part[1][r][c]);
    }
    __syncthreads();

    {
        const half_t* xprow = &xp[stripe * 16 + l16][0];
        f16x8 a0 = *(const f16x8*)(xprow + 8 * g);
        f16x8 a1 = *(const f16x8*)(xprow + 32 + 8 * g);

        int cb0 = ks * (OUT_FEAT / 2);
        for (int cb = cb0; cb < cb0 + OUT_FEAT / 2; cb += 16) {
            int col = cb + l16;
            const float* wp = wB + (size_t)col * RANK;
            float4 w00 = *(const float4*)(wp + 8 * g);
            float4 w01 = *(const float4*)(wp + 8 * g + 4);
            float4 w10 = *(const float4*)(wp + 32 + 8 * g);
            float4 w11 = *(const float4*)(wp + 32 + 8 * g + 4);
            f16x4 b00 = thr4(w00, sB), b01 = thr4(w01, sB);
            f16x4 b10 = thr4(w10, sB), b11 = thr4(w11, sB);
            f16x8 b0, b1;
            b0[0]=b00[0]; b0[1]=b00[1]; b0[2]=b00[2]; b0[3]=b00[3];
            b0[4]=b01[0]; b0[5]=b01[1]; b0[6]=b01[2]; b0[7]=b01[3];
            b1[0]=b10[0]; b1[1]=b10[1]; b1[2]=b10[2]; b1[3]=b10[3];
            b1[4]=b11[0]; b1[5]=b11[1]; b1[6]=b11[2]; b1[7]=b11[3];

            f32x4 acc2 = {0, 0, 0, 0};
            acc2 = __builtin_amdgcn_mfma_f32_16x16x32_f16(a0, b0, acc2, 0, 0, 0);
            acc2 = __builtin_amdgcn_mfma_f32_16x16x32_f16(a1, b1, acc2, 0, 0, 0);
            float bv = bias[col];
#pragma unroll
            for (int r = 0; r < 4; ++r)
                out[(size_t)(rowbase + stripe * 16 + 4 * g + r) * OUT_FEAT + col] = acc2[r] + bv;
        }
    }
}

extern "C" void kernel_launch(void* const* d_in, const int* in_sizes, int n_in,
                              void* d_out, int out_size, void* d_ws, size_t ws_size,
                              hipStream_t stream) {
    const float* x      = (const float*)d_in[0];
    const float* wA     = (const float*)d_in[1];
    const float* wB     = (const float*)d_in[2];
    const float* bias   = (const float*)d_in[3];
    const float* scaleA = (const float*)d_in[4];
    const float* scaleB = (const float*)d_in[5];
    float* out = (float*)d_out;

    const size_t WS_V3 = (size_t)RANK * IN_FEAT * 2
                       + (size_t)OUT_FEAT * RANK * 2
                       + (size_t)NROWS * RANK * 2;

    bool launched = false;
    if (ws_size >= WS_V3 && d_ws != nullptr) {
        half_t* wAT = (half_t*)d_ws;
        half_t* wBh = wAT + (size_t)RANK * IN_FEAT;
        half_t* xpw = wBh + (size_t)OUT_FEAT * RANK;
        void* args[] = {(void*)&x, (void*)&wA, (void*)&wB, (void*)&bias,
                        (void*)&scaleA, (void*)&scaleB, (void*)&out,
                        (void*)&wAT, (void*)&wBh, (void*)&xpw};
        hipError_t err = hipLaunchCooperativeKernel((void*)coop_v3,
                                                    dim3(NB), dim3(BT),
                                                    args, 0, stream);
        launched = (err == hipSuccess);
    }
    if (!launched) {
        fused_kernel<<<NROWS / TM, 256, 0, stream>>>(x, wA, wB, bias, scaleA, scaleB, out);
    }
}

// Round 15
// 218.452 us; speedup vs baseline: 1.2967x; 1.2967x over previous
//
#include <hip/hip_runtime.h>
#include <hip/hip_cooperative_groups.h>

namespace cg = cooperative_groups;

#define IN_FEAT 4096
#define OUT_FEAT 4096
#define RANK 64
#define NROWS 16384
#define TM 32              // phase-A rows per sub-tile
#define BT 512             // threads per block (8 waves)
#define NB 256             // grid blocks (1 per CU)
#define KC2 256            // phase-A K-chunk (f32 elems)
#define SXS 264            // xs inner stride (f16)
#define BR 256             // phase-B tile rows
#define BC 256             // phase-B tile cols
#define BS 72              // phase-B LDS inner stride (f16)
#define KC 256             // fallback kernel chunk
#define WA_STRIDE 264
#define XP_STRIDE 72

typedef _Float16 half_t;
typedef _Float16 f16x4 __attribute__((ext_vector_type(4)));
typedef _Float16 f16x8 __attribute__((ext_vector_type(8)));
typedef float f32x4 __attribute__((ext_vector_type(4)));

__device__ __forceinline__ f16x4 thr4(float4 v, float s) {
    float a0 = fabsf(v.x), a1 = fabsf(v.y), a2 = fabsf(v.z), a3 = fabsf(v.w);
    float lo1 = fminf(a0, a1), hi1 = fmaxf(a0, a1);
    float lo2 = fminf(a2, a3), hi2 = fmaxf(a2, a3);
    float t = fminf(fmaxf(lo1, lo2), fminf(hi1, hi2));  // 2nd-smallest = 3rd-largest
    f16x4 r;
    r[0] = (half_t)(copysignf(fmaxf(a0 - t, 0.0f), v.x) * s);
    r[1] = (half_t)(copysignf(fmaxf(a1 - t, 0.0f), v.y) * s);
    r[2] = (half_t)(copysignf(fmaxf(a2 - t, 0.0f), v.z) * s);
    r[3] = (half_t)(copysignf(fmaxf(a3 - t, 0.0f), v.w) * s);
    return r;
}

__device__ __forceinline__ f16x4 cvt4(f32x4 v) {
    f16x4 h;
    h[0] = (half_t)v[0]; h[1] = (half_t)v[1];
    h[2] = (half_t)v[2]; h[3] = (half_t)v[3];
    return h;
}

// ============ v3c: swapped-operand phase B -> float4 stores =================
// 256 blocks x 512 threads, 74.8 KB LDS, 1 block/CU (coop-safe).
// Phase B MFMA computes D = wbs_frag x xp_frag, so each lane owns
// out[row=l16][col0+4g .. +3] -> ONE dwordx4 store per MFMA pair (was 4
// scalar dwords). Everything else identical to the round-13 passing kernel.
__global__ __launch_bounds__(BT) void coop_v3(
    const float* __restrict__ x, const float* __restrict__ wA,
    const float* __restrict__ wB, const float* __restrict__ bias,
    const float* __restrict__ scaleA, const float* __restrict__ scaleB,
    float* __restrict__ out, half_t* __restrict__ wAT, half_t* __restrict__ wBh,
    half_t* __restrict__ xpw)
{
    __shared__ __align__(16) char pool[BR * BS * 2 + BC * BS * 2]; // 72 KB
    __shared__ __align__(16) float biasl[BC];                      // 1 KB

    int tid = threadIdx.x;
    int bid = blockIdx.x;

    // ---- Phase 0: prep weights ----------------------------------------------
    {
        int id = bid * BT + tid;
        if (id < 65536) {
            int row = id >> 4;
            int gq  = id & 15;
            float s = scaleB[0];
            f16x4 h = thr4(*(const float4*)(wB + (size_t)row * RANK + gq * 4), s);
            *(f16x4*)(wBh + (size_t)row * RANK + gq * 4) = h;
        } else if (id < 65536 + 8192) {
            int t2 = id - 65536;
            int c4 = t2 & 15;
            int k8 = t2 >> 4;
            float s = scaleA[0];
            f16x8 vc0, vc1, vc2, vc3;
#pragma unroll
            for (int i = 0; i < 8; ++i) {
                float4 v = *(const float4*)(wA + (size_t)(k8 * 8 + i) * RANK + c4 * 4);
                f16x4 h = thr4(v, s);
                vc0[i] = h[0]; vc1[i] = h[1]; vc2[i] = h[2]; vc3[i] = h[3];
            }
            *(f16x8*)(wAT + (size_t)(c4 * 4 + 0) * IN_FEAT + k8 * 8) = vc0;
            *(f16x8*)(wAT + (size_t)(c4 * 4 + 1) * IN_FEAT + k8 * 8) = vc1;
            *(f16x8*)(wAT + (size_t)(c4 * 4 + 2) * IN_FEAT + k8 * 8) = vc2;
            *(f16x8*)(wAT + (size_t)(c4 * 4 + 3) * IN_FEAT + k8 * 8) = vc3;
        }
    }
    cg::this_grid().sync();

    int wave = tid >> 6;
    int lane = tid & 63;
    int l16  = lane & 15;
    int g    = lane >> 4;

    // ---- Phase A: two 32-row tiles -> xpw -----------------------------------
    {
        half_t (*xs)[TM][SXS] = (half_t(*)[TM][SXS])pool;
        int stripe = wave & 1;
        int quad   = wave >> 1;
        int srow = tid >> 4;
        int sseg = tid & 15;

        for (int sub = 0; sub < 2; ++sub) {
            int rowbase = bid * (2 * TM) + sub * TM;
            const float* srcrow = x + (size_t)(rowbase + srow) * IN_FEAT + sseg * 4;

            {   // prologue: stage chunk 0
                const f32x4* p = (const f32x4*)(srcrow);
                f32x4 a0 = p[0], a1 = p[16], a2 = p[32], a3 = p[48];
                half_t* dst = &xs[0][srow][sseg * 4];
                *(f16x4*)(dst +   0) = cvt4(a0);
                *(f16x4*)(dst +  64) = cvt4(a1);
                *(f16x4*)(dst + 128) = cvt4(a2);
                *(f16x4*)(dst + 192) = cvt4(a3);
            }
            __syncthreads();

            f32x4 acc = {0, 0, 0, 0};
            const half_t* wcol = wAT + (size_t)(quad * 16 + l16) * IN_FEAT;
            const half_t* arow = &xs[0][stripe * 16 + l16][0];
            const int xsstep = TM * SXS;
            f32x4 ld0, ld1, ld2, ld3;

            for (int c = 0; c < IN_FEAT / KC2; ++c) {
                f16x8 bfr[8];
#pragma unroll
                for (int j = 0; j < 8; ++j)
                    bfr[j] = *(const f16x8*)(wcol + c * KC2 + j * 32 + 8 * g);
                __builtin_amdgcn_sched_barrier(0);
                if (c + 1 < IN_FEAT / KC2) {
                    const f32x4* p = (const f32x4*)(srcrow + (c + 1) * KC2);
                    ld0 = p[0]; ld1 = p[16]; ld2 = p[32]; ld3 = p[48];
                }
                __builtin_amdgcn_sched_barrier(0);

                const half_t* ar = arow + (c & 1) * xsstep;
#pragma unroll
                for (int j = 0; j < 8; ++j) {
                    f16x8 a = *(const f16x8*)(ar + j * 32 + 8 * g);
                    acc = __builtin_amdgcn_mfma_f32_16x16x32_f16(a, bfr[j], acc, 0, 0, 0);
                }
                if (c + 1 < IN_FEAT / KC2) {
                    half_t* dst = &xs[(c + 1) & 1][srow][sseg * 4];
                    *(f16x4*)(dst +   0) = cvt4(ld0);
                    *(f16x4*)(dst +  64) = cvt4(ld1);
                    *(f16x4*)(dst + 128) = cvt4(ld2);
                    *(f16x4*)(dst + 192) = cvt4(ld3);
                }
                __syncthreads();
            }

            // C/D: col = lane&15, row = 4*(lane>>4)+reg; full-K f32 -> f16
#pragma unroll
            for (int r = 0; r < 4; ++r)
                xpw[(size_t)(rowbase + stripe * 16 + 4 * g + r) * RANK + quad * 16 + l16]
                    = (half_t)acc[r];
            __syncthreads();   // xs fully free before next sub-tile
        }
    }
    cg::this_grid().sync();

    // ---- Phase B: 256-row slab x 4 fat 256-col tiles, swapped MFMA ----------
    {
        half_t (*xps)[BS] = (half_t(*)[BS])pool;                       // 36 KB
        half_t (*wbs)[BS] = (half_t(*)[BS])(pool + BR * BS * 2);       // 36 KB

        int rb = (bid >> 2) * BR;

        // stage xps once: 256 rows x 64 f16 (32 KB)
        {
            int row = tid >> 1, h = tid & 1;
            const half_t* src = xpw + (size_t)(rb + row) * RANK + h * 32;
            f16x8 v0 = *(const f16x8*)(src + 0);
            f16x8 v1 = *(const f16x8*)(src + 8);
            f16x8 v2 = *(const f16x8*)(src + 16);
            f16x8 v3 = *(const f16x8*)(src + 24);
            half_t* dst = &xps[row][h * 32];
            *(f16x8*)(dst + 0)  = v0;
            *(f16x8*)(dst + 8)  = v1;
            *(f16x8*)(dst + 16) = v2;
            *(f16x8*)(dst + 24) = v3;
        }

        int wrow = (wave & 1) * 128;       // wave's 128-row half
        int wcol = (wave >> 1) * 64;       // wave's 64-col quarter

        for (int t = 0; t < 4; ++t) {
            int cb = ((bid & 3) * 4 + t) * BC;

            // stage wbs: 256 cols x 64 f16 (32 KB) + bias (1 KB)
            {
                int col = tid >> 1, h = tid & 1;
                const half_t* src = wBh + (size_t)(cb + col) * RANK + h * 32;
                f16x8 v0 = *(const f16x8*)(src + 0);
                f16x8 v1 = *(const f16x8*)(src + 8);
                f16x8 v2 = *(const f16x8*)(src + 16);
                f16x8 v3 = *(const f16x8*)(src + 24);
                half_t* dst = &wbs[col][h * 32];
                *(f16x8*)(dst + 0)  = v0;
                *(f16x8*)(dst + 8)  = v1;
                *(f16x8*)(dst + 16) = v2;
                *(f16x8*)(dst + 24) = v3;
                if (tid < BC) biasl[tid] = bias[cb + tid];
            }
            __syncthreads();

            // b-fragments (wbs, acts as MFMA *A* operand: m = out-col) + bias4
            f16x8 bf0[4], bf1[4];
            f32x4 bv4[4];
#pragma unroll
            for (int ci = 0; ci < 4; ++ci) {
                int c16 = wcol + ci * 16 + l16;
                bf0[ci] = *(const f16x8*)&wbs[c16][8 * g];
                bf1[ci] = *(const f16x8*)&wbs[c16][32 + 8 * g];
                bv4[ci] = *(const f32x4*)&biasl[wcol + ci * 16 + 4 * g];
            }

            // swapped MFMA: D = wbs x xp -> lane owns out[row=l16][4 consecutive cols]
            for (int rt = 0; rt < 8; ++rt) {
                const half_t* ar = &xps[wrow + rt * 16 + l16][0];
                f16x8 a0 = *(const f16x8*)(ar + 8 * g);
                f16x8 a1 = *(const f16x8*)(ar + 32 + 8 * g);
                size_t rowoff = (size_t)(rb + wrow + rt * 16 + l16) * OUT_FEAT;
#pragma unroll
                for (int ci = 0; ci < 4; ++ci) {
                    f32x4 acc2 = {0, 0, 0, 0};
                    acc2 = __builtin_amdgcn_mfma_f32_16x16x32_f16(bf0[ci], a0, acc2, 0, 0, 0);
                    acc2 = __builtin_amdgcn_mfma_f32_16x16x32_f16(bf1[ci], a1, acc2, 0, 0, 0);
                    f32x4 st;
                    st[0] = acc2[0] + bv4[ci][0];
                    st[1] = acc2[1] + bv4[ci][1];
                    st[2] = acc2[2] + bv4[ci][2];
                    st[3] = acc2[3] + bv4[ci][3];
                    int col0 = cb + wcol + ci * 16 + 4 * g;
                    *(f32x4*)&out[rowoff + col0] = st;
                }
            }
            __syncthreads();
        }
    }
}

// ================= fallback: zero-ws fused (round-4, passing) ===============
__global__ __launch_bounds__(256) void fused_kernel(
    const float* __restrict__ x, const float* __restrict__ wA,
    const float* __restrict__ wB, const float* __restrict__ bias,
    const float* __restrict__ scaleA, const float* __restrict__ scaleB,
    float* __restrict__ out)
{
    __shared__ __align__(16) half_t wAsT[RANK][WA_STRIDE];
    __shared__ float xp_part[2][TM][XP_STRIDE];
    __shared__ __align__(16) half_t xp[TM][XP_STRIDE];

    int tid  = threadIdx.x;
    int wave = tid >> 6;
    int lane = tid & 63;
    int l16  = lane & 15;
    int g    = lane >> 4;
    int rowbase = blockIdx.x * TM;
    int stripe  = wave & 1;
    int ks      = wave >> 1;

    float sA = scaleA[0];
    float sB = scaleB[0];

    const float* xrow = x + (size_t)(rowbase + stripe * 16 + l16) * IN_FEAT;
    f32x4 acc[4] = {f32x4{0,0,0,0}, f32x4{0,0,0,0}, f32x4{0,0,0,0}, f32x4{0,0,0,0}};

    for (int chunk = 0; chunk < IN_FEAT / KC; ++chunk) {
        int k0 = chunk * KC;
#pragma unroll
        for (int pp = 0; pp < 2; ++pp) {
            int p = tid + pp * 256;
            int q = p & 15;
            int r = p >> 4;
            f16x8 vc0, vc1, vc2, vc3;
#pragma unroll
            for (int i = 0; i < 8; ++i) {
                float4 v = *(const float4*)(wA + (size_t)(k0 + 8 * r + i) * RANK + 4 * q);
                f16x4 h = thr4(v, sA);
                vc0[i] = h[0]; vc1[i] = h[1]; vc2[i] = h[2]; vc3[i] = h[3];
            }
            *(f16x8*)&wAsT[4 * q + 0][8 * r] = vc0;
            *(f16x8*)&wAsT[4 * q + 1][8 * r] = vc1;
            *(f16x8*)&wAsT[4 * q + 2][8 * r] = vc2;
            *(f16x8*)&wAsT[4 * q + 3][8 * r] = vc3;
        }
        __syncthreads();

#pragma unroll
        for (int it = 0; it < 4; ++it) {
            int kloc = ks * 128 + it * 32;
            float4 xa = *(const float4*)(xrow + k0 + kloc + 8 * g);
            float4 xb = *(const float4*)(xrow + k0 + kloc + 8 * g + 4);
            f16x8 a;
            a[0] = (half_t)xa.x; a[1] = (half_t)xa.y; a[2] = (half_t)xa.z; a[3] = (half_t)xa.w;
            a[4] = (half_t)xb.x; a[5] = (half_t)xb.y; a[6] = (half_t)xb.z; a[7] = (half_t)xb.w;
#pragma unroll
            for (int f = 0; f < 4; ++f) {
                f16x8 b = *(const f16x8*)&wAsT[16 * f + l16][kloc + 8 * g];
                acc[f] = __builtin_amdgcn_mfma_f32_16x16x32_f16(a, b, acc[f], 0, 0, 0);
            }
        }
        __syncthreads();
    }

#pragma unroll
    for (int f = 0; f < 4; ++f)
#pragma unroll
        for (int r = 0; r < 4; ++r)
            xp_part[ks][stripe * 16 + 4 * g + r][16 * f + l16] = acc[f][r];
    __syncthreads();

#pragma unroll
    for (int i = 0; i < (TM * RANK) / 256; ++i) {
        int e = i * 256 + tid;
        int r = e >> 6, c = e & 63;
        xp[r][c] = (half_t)(xp_part[0][r][c] + xp_part[1][r][c]);
    }
    __syncthreads();

    {
        const half_t* xprow = &xp[stripe * 16 + l16][0];
        f16x8 a0 = *(const f16x8*)(xprow + 8 * g);
        f16x8 a1 = *(const f16x8*)(xprow + 32 + 8 * g);

        int cb0 = ks * (OUT_FEAT / 2);
        for (int cb = cb0; cb < cb0 + OUT_FEAT / 2; cb += 16) {
            int col = cb + l16;
            const float* wp = wB + (size_t)col * RANK;
            float4 w00 = *(const float4*)(wp + 8 * g);
            float4 w01 = *(const float4*)(wp + 8 * g + 4);
            float4 w10 = *(const float4*)(wp + 32 + 8 * g);
            float4 w11 = *(const float4*)(wp + 32 + 8 * g + 4);
            f16x4 b00 = thr4(w00, sB), b01 = thr4(w01, sB);
            f16x4 b10 = thr4(w10, sB), b11 = thr4(w11, sB);
            f16x8 b0, b1;
            b0[0]=b00[0]; b0[1]=b00[1]; b0[2]=b00[2]; b0[3]=b00[3];
            b0[4]=b01[0]; b0[5]=b01[1]; b0[6]=b01[2]; b0[7]=b01[3];
            b1[0]=b10[0]; b1[1]=b10[1]; b1[2]=b10[2]; b1[3]=b10[3];
            b1[4]=b11[0]; b1[5]=b11[1]; b1[6]=b11[2]; b1[7]=b11[3];

            f32x4 acc2 = {0, 0, 0, 0};
            acc2 = __builtin_amdgcn_mfma_f32_16x16x32_f16(a0, b0, acc2, 0, 0, 0);
            acc2 = __builtin_amdgcn_mfma_f32_16x16x32_f16(a1, b1, acc2, 0, 0, 0);
            float bv = bias[col];
#pragma unroll
            for (int r = 0; r < 4; ++r)
                out[(size_t)(rowbase + stripe * 16 + 4 * g + r) * OUT_FEAT + col] = acc2[r] + bv;
        }
    }
}

extern "C" void kernel_launch(void* const* d_in, const int* in_sizes, int n_in,
                              void* d_out, int out_size, void* d_ws, size_t ws_size,
                              hipStream_t stream) {
    const float* x      = (const float*)d_in[0];
    const float* wA     = (const float*)d_in[1];
    const float* wB     = (const float*)d_in[2];
    const float* bias   = (const float*)d_in[3];
    const float* scaleA = (const float*)d_in[4];
    const float* scaleB = (const float*)d_in[5];
    float* out = (float*)d_out;

    const size_t WS_V3 = (size_t)RANK * IN_FEAT * 2
                       + (size_t)OUT_FEAT * RANK * 2
                       + (size_t)NROWS * RANK * 2;

    bool launched = false;
    if (ws_size >= WS_V3 && d_ws != nullptr) {
        half_t* wAT = (half_t*)d_ws;
        half_t* wBh = wAT + (size_t)RANK * IN_FEAT;
        half_t* xpw = wBh + (size_t)OUT_FEAT * RANK;
        void* args[] = {(void*)&x, (void*)&wA, (void*)&wB, (void*)&bias,
                        (void*)&scaleA, (void*)&scaleB, (void*)&out,
                        (void*)&wAT, (void*)&wBh, (void*)&xpw};
        hipError_t err = hipLaunchCooperativeKernel((void*)coop_v3,
                                                    dim3(NB), dim3(BT),
                                                    args, 0, stream);
        launched = (err == hipSuccess);
    }
    if (!launched) {
        fused_kernel<<<NROWS / TM, 256, 0, stream>>>(x, wA, wB, bias, scaleA, scaleB, out);
    }
}